// Round 16
// baseline (198.827 us; speedup 1.0000x reference)
//
#include <hip/hip_runtime.h>
#include <hip/hip_bf16.h>

#define B 32
#define C 512
#define HW 3136            // 56*56 floats per plane
#define HW4 784            // fx4 per plane
#define TH 0.01f
#define NPG 32             // partial groups (blocks per batch)
#define CPB 16             // channels per block

typedef float fx4 __attribute__((ext_vector_type(4)));

// ---------------------------------------------------------------------------
// Kernel A: R9 quarter-plane-per-wave + register double-buffer prefetch.
// ALL buffer registers are individually NAMED scalars via token-pasted
// macros - no arrays, no pointer selection (R11/R15 lesson: both spill).
// Per group: prefetch next 2 channels' 8 loads, then reduce current group
// (compiler emits vmcnt(8): next group's loads stay in flight), shfl chain,
// 16-float LDS exchange with lgkmcnt(0)+raw s_barrier (no vmcnt drain -
// __syncthreads would drain the prefetch), alphas, FMA. ~110 VGPR < 128.
// ---------------------------------------------------------------------------

#define LOADG(buf, c0)                                                        \
  {                                                                           \
    const fx4* __restrict__ p0_ = xb4 + (size_t)(c0) * HW4 + qbase + l;       \
    const fx4* __restrict__ p1_ = p0_ + HW4;                                  \
    buf##a0 = p0_[0];  buf##a1 = p0_[64]; buf##a2 = p0_[128];                 \
    buf##b0 = p1_[0];  buf##b1 = p1_[64]; buf##b2 = p1_[128];                 \
    buf##a3 = zf; buf##b3 = zf;                                               \
    if (l < 4) { buf##a3 = p0_[192]; buf##b3 = p1_[192]; }                    \
  }

#define REDUCE(buf, g)                                                        \
  {                                                                           \
    float sa = (((buf##a0.x + buf##a0.y) + (buf##a0.z + buf##a0.w)) +         \
                ((buf##a1.x + buf##a1.y) + (buf##a1.z + buf##a1.w))) +        \
               (((buf##a2.x + buf##a2.y) + (buf##a2.z + buf##a2.w)) +         \
                ((buf##a3.x + buf##a3.y) + (buf##a3.z + buf##a3.w)));         \
    float sb = (((buf##b0.x + buf##b0.y) + (buf##b0.z + buf##b0.w)) +         \
                ((buf##b1.x + buf##b1.y) + (buf##b1.z + buf##b1.w))) +        \
               (((buf##b2.x + buf##b2.y) + (buf##b2.z + buf##b2.w)) +         \
                ((buf##b3.x + buf##b3.y) + (buf##b3.z + buf##b3.w)));         \
    _Pragma("unroll")                                                         \
    for (int off = 1; off < 64; off <<= 1) {                                  \
      sa += __shfl_xor(sa, off);                                              \
      sb += __shfl_xor(sb, off);                                              \
    }                                                                         \
    if (l == 0) {                                                             \
      sums[(g) & 1][0][wv] = sa;                                              \
      sums[(g) & 1][1][wv] = sb;                                              \
    }                                                                         \
    asm volatile("s_waitcnt lgkmcnt(0)" ::: "memory");                        \
    __builtin_amdgcn_sched_barrier(0);                                        \
    __builtin_amdgcn_s_barrier();                                             \
    __builtin_amdgcn_sched_barrier(0);                                        \
    const float al0 = ((sums[(g) & 1][0][0] + sums[(g) & 1][0][1]) +          \
                       (sums[(g) & 1][0][2] + sums[(g) & 1][0][3])) *         \
                      (1.0f / (float)HW);                                     \
    const float al1 = ((sums[(g) & 1][1][0] + sums[(g) & 1][1][1]) +          \
                       (sums[(g) & 1][1][2] + sums[(g) & 1][1][3])) *         \
                      (1.0f / (float)HW);                                     \
    acc0 += buf##a0 * al0 + buf##b0 * al1;                                    \
    acc1 += buf##a1 * al0 + buf##b1 * al1;                                    \
    acc2 += buf##a2 * al0 + buf##b2 * al1;                                    \
    acc3 += buf##a3 * al0 + buf##b3 * al1;                                    \
  }

__global__ __launch_bounds__(256, 4) void partial_kernel(const float* __restrict__ x,
                                                         float* __restrict__ out) {
    const int b  = blockIdx.y;
    const int pg = blockIdx.x;          // 0..NPG-1
    const int t  = threadIdx.x;
    const int l  = t & 63;
    const int wv = t >> 6;

    __shared__ float sums[2][2][4];     // [parity][channel][wave]

    const fx4* __restrict__ xb4 = (const fx4*)(x + (size_t)b * C * HW);
    const int qbase = wv * 196;         // this wave's fx4-col base
    const fx4 zf = (fx4)0.f;
    const int cb = pg * CPB;

    fx4 acc0 = zf, acc1 = zf, acc2 = zf, acc3 = zf;

    // named double buffers X*, Y* (8 fx4 each)
    fx4 Xa0, Xa1, Xa2, Xa3, Xb0, Xb1, Xb2, Xb3;
    fx4 Ya0, Ya1, Ya2, Ya3, Yb0, Yb1, Yb2, Yb3;

    LOADG(X, cb + 0)
    LOADG(Y, cb + 2)  REDUCE(X, 0)
    LOADG(X, cb + 4)  REDUCE(Y, 1)
    LOADG(Y, cb + 6)  REDUCE(X, 2)
    LOADG(X, cb + 8)  REDUCE(Y, 3)
    LOADG(Y, cb + 10) REDUCE(X, 4)
    LOADG(X, cb + 12) REDUCE(Y, 5)
    LOADG(Y, cb + 14) REDUCE(X, 6)
    REDUCE(Y, 7)

    // direct disjoint store of this wave's quarter (cached; B re-reads it)
    fx4* __restrict__ dst = (fx4*)(out + (size_t)b * C * HW + (size_t)pg * HW) + qbase + l;
    dst[0]   = acc0;
    dst[64]  = acc1;
    dst[128] = acc2;
    if (l < 4) dst[192] = acc3;
}

// ---------------------------------------------------------------------------
// Kernel B: R9-verbatim (validated best; NT stores REQUIRED - R14 showed
// cached stores evict x from L3 and cost +22 us).
// ---------------------------------------------------------------------------
__global__ __launch_bounds__(256) void out_kernel(const float* __restrict__ w,
                                                  const float* __restrict__ scale_p,
                                                  const float* __restrict__ wf_p,
                                                  float* __restrict__ out) {
    const int b    = blockIdx.y;
    const int tile = blockIdx.x;               // 0..48
    const int t    = threadIdx.x;
    const int hw4  = t & 15;
    const int pg2  = t >> 4;                   // 0..15 -> partials 2*pg2, 2*pg2+1
    const int lane = t & 63;
    const int wid  = t >> 6;

    const fx4* __restrict__ P =
        (const fx4*)(out + (size_t)b * C * HW) + tile * 16 + hw4;
    fx4 s = P[(size_t)(2 * pg2) * HW4] + P[(size_t)(2 * pg2 + 1) * HW4];

    // reduce the 4 pg2-groups in this wave (lane deltas 16, 32)
    s.x += __shfl_xor(s.x, 16); s.y += __shfl_xor(s.y, 16);
    s.z += __shfl_xor(s.z, 16); s.w += __shfl_xor(s.w, 16);
    s.x += __shfl_xor(s.x, 32); s.y += __shfl_xor(s.y, 32);
    s.z += __shfl_xor(s.z, 32); s.w += __shfl_xor(s.w, 32);

    __shared__ fx4 red[4][16];
    if (lane < 16) red[wid][lane] = s;
    __syncthreads();

    __shared__ fx4 sal_sm[16];
    if (t < 16) {
        sal_sm[t] = ((red[0][t] + red[1][t]) + (red[2][t] + red[3][t])) *
                    (1.0f / (float)C);
    }
    __syncthreads();

    const float scale = scale_p[0];
    const float wf    = wf_p[0];
    const float out_zero = 1.0f - 0.5f * wf;   // fm == 0 path
    const fx4 s4 = sal_sm[hw4];

    fx4* __restrict__ ob = (fx4*)(out + (size_t)b * C * HW) + tile * 16 + hw4;
    const int c0 = pg2 * 32;                   // each group covers its 32 co's

    #pragma unroll 4
    for (int k = 0; k < 32; ++k) {
        const int co = c0 + k;
        const float wc = w[co];
        fx4 r;
        float fm;
        fm = s4.x * wc;
        r.x = (fm > TH) ? 1.0f - wf / (1.0f + __expf(-scale * fm)) : out_zero;
        fm = s4.y * wc;
        r.y = (fm > TH) ? 1.0f - wf / (1.0f + __expf(-scale * fm)) : out_zero;
        fm = s4.z * wc;
        r.z = (fm > TH) ? 1.0f - wf / (1.0f + __expf(-scale * fm)) : out_zero;
        fm = s4.w * wc;
        r.w = (fm > TH) ? 1.0f - wf / (1.0f + __expf(-scale * fm)) : out_zero;
        __builtin_nontemporal_store(r, ob + (size_t)co * HW4);
    }
}

extern "C" void kernel_launch(void* const* d_in, const int* in_sizes, int n_in,
                              void* d_out, int out_size, void* d_ws, size_t ws_size,
                              hipStream_t stream) {
    const float* x      = (const float*)d_in[0];
    const float* conv_w = (const float*)d_in[1];   // 512 floats
    const float* scale  = (const float*)d_in[2];
    const float* wf     = (const float*)d_in[3];
    float* out = (float*)d_out;

    dim3 gridA(NPG, B);                            // 32 x 32 = 1024 blocks
    partial_kernel<<<gridA, 256, 0, stream>>>(x, out);

    dim3 gridB(HW4 / 16, B);                       // 49 x 32 = 1568 blocks
    out_kernel<<<gridB, 256, 0, stream>>>(conv_w, scale, wf, out);
}

// Round 17
// 195.854 us; speedup vs baseline: 1.0152x; 1.0152x over previous
//
#include <hip/hip_runtime.h>
#include <hip/hip_bf16.h>

#define B 32
#define C 512
#define HW 3136            // 56*56 floats per plane
#define HW4 784            // fx4 per plane
#define TH 0.01f
#define NPG 32             // partial groups (blocks per batch)
#define CPB 16             // channels per block

typedef float fx4 __attribute__((ext_vector_type(4)));

// ---------------------------------------------------------------------------
// Kernel A: R16 double-buffered prefetch + amdgpu_waves_per_eu(4,4).
// R15/R16 showed the backend targets 8 waves/EU (64 VGPR) and SPILLS the
// ~110-reg double-buffer working set to scratch (FETCH/WRITE ballooned to
// 290/240 MB). Pinning waves-per-EU to [4,4] sets the register budget to
// 128 so the allocator keeps the buffers in VGPRs.
// Pipeline per group: prefetch next 2 channels (8 loads stay in flight),
// tree-sum current group (vmcnt(8)), shfl chain, 16-float LDS exchange via
// lgkmcnt(0)+raw s_barrier (NO vmcnt drain - __syncthreads would kill the
// prefetch), alphas, FMA into per-wave acc.
// ---------------------------------------------------------------------------

#define LOADG(buf, c0)                                                        \
  {                                                                           \
    const fx4* __restrict__ p0_ = xb4 + (size_t)(c0) * HW4 + qbase + l;       \
    const fx4* __restrict__ p1_ = p0_ + HW4;                                  \
    buf##a0 = p0_[0];  buf##a1 = p0_[64]; buf##a2 = p0_[128];                 \
    buf##b0 = p1_[0];  buf##b1 = p1_[64]; buf##b2 = p1_[128];                 \
    buf##a3 = zf; buf##b3 = zf;                                               \
    if (l < 4) { buf##a3 = p0_[192]; buf##b3 = p1_[192]; }                    \
  }

#define REDUCE(buf, g)                                                        \
  {                                                                           \
    float sa = (((buf##a0.x + buf##a0.y) + (buf##a0.z + buf##a0.w)) +         \
                ((buf##a1.x + buf##a1.y) + (buf##a1.z + buf##a1.w))) +        \
               (((buf##a2.x + buf##a2.y) + (buf##a2.z + buf##a2.w)) +         \
                ((buf##a3.x + buf##a3.y) + (buf##a3.z + buf##a3.w)));         \
    float sb = (((buf##b0.x + buf##b0.y) + (buf##b0.z + buf##b0.w)) +         \
                ((buf##b1.x + buf##b1.y) + (buf##b1.z + buf##b1.w))) +        \
               (((buf##b2.x + buf##b2.y) + (buf##b2.z + buf##b2.w)) +         \
                ((buf##b3.x + buf##b3.y) + (buf##b3.z + buf##b3.w)));         \
    _Pragma("unroll")                                                         \
    for (int off = 1; off < 64; off <<= 1) {                                  \
      sa += __shfl_xor(sa, off);                                              \
      sb += __shfl_xor(sb, off);                                              \
    }                                                                         \
    if (l == 0) {                                                             \
      sums[(g) & 1][0][wv] = sa;                                              \
      sums[(g) & 1][1][wv] = sb;                                              \
    }                                                                         \
    asm volatile("s_waitcnt lgkmcnt(0)" ::: "memory");                        \
    __builtin_amdgcn_sched_barrier(0);                                        \
    __builtin_amdgcn_s_barrier();                                             \
    __builtin_amdgcn_sched_barrier(0);                                        \
    const float al0 = ((sums[(g) & 1][0][0] + sums[(g) & 1][0][1]) +          \
                       (sums[(g) & 1][0][2] + sums[(g) & 1][0][3])) *         \
                      (1.0f / (float)HW);                                     \
    const float al1 = ((sums[(g) & 1][1][0] + sums[(g) & 1][1][1]) +          \
                       (sums[(g) & 1][1][2] + sums[(g) & 1][1][3])) *         \
                      (1.0f / (float)HW);                                     \
    acc0 += buf##a0 * al0 + buf##b0 * al1;                                    \
    acc1 += buf##a1 * al0 + buf##b1 * al1;                                    \
    acc2 += buf##a2 * al0 + buf##b2 * al1;                                    \
    acc3 += buf##a3 * al0 + buf##b3 * al1;                                    \
  }

__global__ __attribute__((amdgpu_waves_per_eu(4, 4))) __launch_bounds__(256)
void partial_kernel(const float* __restrict__ x,
                    float* __restrict__ out) {
    const int b  = blockIdx.y;
    const int pg = blockIdx.x;          // 0..NPG-1
    const int t  = threadIdx.x;
    const int l  = t & 63;
    const int wv = t >> 6;

    __shared__ float sums[2][2][4];     // [parity][channel][wave]

    const fx4* __restrict__ xb4 = (const fx4*)(x + (size_t)b * C * HW);
    const int qbase = wv * 196;         // this wave's fx4-col base
    const fx4 zf = (fx4)0.f;
    const int cb = pg * CPB;

    fx4 acc0 = zf, acc1 = zf, acc2 = zf, acc3 = zf;

    // named double buffers X*, Y* (8 fx4 each)
    fx4 Xa0, Xa1, Xa2, Xa3, Xb0, Xb1, Xb2, Xb3;
    fx4 Ya0, Ya1, Ya2, Ya3, Yb0, Yb1, Yb2, Yb3;

    LOADG(X, cb + 0)
    LOADG(Y, cb + 2)  REDUCE(X, 0)
    LOADG(X, cb + 4)  REDUCE(Y, 1)
    LOADG(Y, cb + 6)  REDUCE(X, 2)
    LOADG(X, cb + 8)  REDUCE(Y, 3)
    LOADG(Y, cb + 10) REDUCE(X, 4)
    LOADG(X, cb + 12) REDUCE(Y, 5)
    LOADG(Y, cb + 14) REDUCE(X, 6)
    REDUCE(Y, 7)

    // direct disjoint store of this wave's quarter (cached; B re-reads it)
    fx4* __restrict__ dst = (fx4*)(out + (size_t)b * C * HW + (size_t)pg * HW) + qbase + l;
    dst[0]   = acc0;
    dst[64]  = acc1;
    dst[128] = acc2;
    if (l < 4) dst[192] = acc3;
}

// ---------------------------------------------------------------------------
// Kernel B: R9-verbatim (validated best; NT stores REQUIRED - R14 showed
// cached stores evict x from L3 and cost +22 us).
// ---------------------------------------------------------------------------
__global__ __launch_bounds__(256) void out_kernel(const float* __restrict__ w,
                                                  const float* __restrict__ scale_p,
                                                  const float* __restrict__ wf_p,
                                                  float* __restrict__ out) {
    const int b    = blockIdx.y;
    const int tile = blockIdx.x;               // 0..48
    const int t    = threadIdx.x;
    const int hw4  = t & 15;
    const int pg2  = t >> 4;                   // 0..15 -> partials 2*pg2, 2*pg2+1
    const int lane = t & 63;
    const int wid  = t >> 6;

    const fx4* __restrict__ P =
        (const fx4*)(out + (size_t)b * C * HW) + tile * 16 + hw4;
    fx4 s = P[(size_t)(2 * pg2) * HW4] + P[(size_t)(2 * pg2 + 1) * HW4];

    // reduce the 4 pg2-groups in this wave (lane deltas 16, 32)
    s.x += __shfl_xor(s.x, 16); s.y += __shfl_xor(s.y, 16);
    s.z += __shfl_xor(s.z, 16); s.w += __shfl_xor(s.w, 16);
    s.x += __shfl_xor(s.x, 32); s.y += __shfl_xor(s.y, 32);
    s.z += __shfl_xor(s.z, 32); s.w += __shfl_xor(s.w, 32);

    __shared__ fx4 red[4][16];
    if (lane < 16) red[wid][lane] = s;
    __syncthreads();

    __shared__ fx4 sal_sm[16];
    if (t < 16) {
        sal_sm[t] = ((red[0][t] + red[1][t]) + (red[2][t] + red[3][t])) *
                    (1.0f / (float)C);
    }
    __syncthreads();

    const float scale = scale_p[0];
    const float wf    = wf_p[0];
    const float out_zero = 1.0f - 0.5f * wf;   // fm == 0 path
    const fx4 s4 = sal_sm[hw4];

    fx4* __restrict__ ob = (fx4*)(out + (size_t)b * C * HW) + tile * 16 + hw4;
    const int c0 = pg2 * 32;                   // each group covers its 32 co's

    #pragma unroll 4
    for (int k = 0; k < 32; ++k) {
        const int co = c0 + k;
        const float wc = w[co];
        fx4 r;
        float fm;
        fm = s4.x * wc;
        r.x = (fm > TH) ? 1.0f - wf / (1.0f + __expf(-scale * fm)) : out_zero;
        fm = s4.y * wc;
        r.y = (fm > TH) ? 1.0f - wf / (1.0f + __expf(-scale * fm)) : out_zero;
        fm = s4.z * wc;
        r.z = (fm > TH) ? 1.0f - wf / (1.0f + __expf(-scale * fm)) : out_zero;
        fm = s4.w * wc;
        r.w = (fm > TH) ? 1.0f - wf / (1.0f + __expf(-scale * fm)) : out_zero;
        __builtin_nontemporal_store(r, ob + (size_t)co * HW4);
    }
}

extern "C" void kernel_launch(void* const* d_in, const int* in_sizes, int n_in,
                              void* d_out, int out_size, void* d_ws, size_t ws_size,
                              hipStream_t stream) {
    const float* x      = (const float*)d_in[0];
    const float* conv_w = (const float*)d_in[1];   // 512 floats
    const float* scale  = (const float*)d_in[2];
    const float* wf     = (const float*)d_in[3];
    float* out = (float*)d_out;

    dim3 gridA(NPG, B);                            // 32 x 32 = 1024 blocks
    partial_kernel<<<gridA, 256, 0, stream>>>(x, out);

    dim3 gridB(HW4 / 16, B);                       // 49 x 32 = 1568 blocks
    out_kernel<<<gridB, 256, 0, stream>>>(conv_w, scale, wf, out);
}